// Round 2
// baseline (291.989 us; speedup 1.0000x reference)
//
#include <hip/hip_runtime.h>
#include <hip/hip_bf16.h>

#define S_LEN 4096
#define DIN   256
#define DOUT  64
#define NBATCH 4
#define KB    64

typedef __attribute__((ext_vector_type(8))) short short8;
typedef __attribute__((ext_vector_type(4))) float f32x4;

__device__ __forceinline__ ushort f2bf(float f) {
  union { float f; unsigned u; } c; c.f = f;
  unsigned u = c.u;
  u += 0x7fffu + ((u >> 16) & 1u);   // round-to-nearest-even
  return (ushort)(u >> 16);
}

// ---------------- projection: Q and K, row-major bf16 out ----------------
__global__ __launch_bounds__(256) void proj_qk(
    const float* __restrict__ Xk, const float* __restrict__ Wk, ushort* __restrict__ Kb,
    const float* __restrict__ Xq, const float* __restrict__ Wq, ushort* __restrict__ Qb)
{
  const float* X; const float* W; ushort* O;
  if (blockIdx.y == 0) { X = Xk; W = Wk; O = Kb; }
  else                 { X = Xq; W = Wq; O = Qb; }
  const int lane = threadIdx.x & 63;
  const int wv   = threadIdx.x >> 6;
  const size_t row0 = (size_t)blockIdx.x * 16 + wv * 4;
  const float* x = X + row0 * DIN;
  float a0 = 0.f, a1 = 0.f, a2 = 0.f, a3 = 0.f;
#pragma unroll 4
  for (int k = 0; k < DIN; k += 4) {
    float4 x0 = *(const float4*)(x + k);
    float4 x1 = *(const float4*)(x + DIN + k);
    float4 x2 = *(const float4*)(x + 2 * DIN + k);
    float4 x3 = *(const float4*)(x + 3 * DIN + k);
    float w0 = W[(k + 0) * DOUT + lane];
    float w1 = W[(k + 1) * DOUT + lane];
    float w2 = W[(k + 2) * DOUT + lane];
    float w3 = W[(k + 3) * DOUT + lane];
    a0 += x0.x * w0 + x0.y * w1 + x0.z * w2 + x0.w * w3;
    a1 += x1.x * w0 + x1.y * w1 + x1.z * w2 + x1.w * w3;
    a2 += x2.x * w0 + x2.y * w1 + x2.z * w2 + x2.w * w3;
    a3 += x3.x * w0 + x3.y * w1 + x3.z * w2 + x3.w * w3;
  }
  ushort* o = O + row0 * DOUT + lane;
  o[0]        = f2bf(a0);
  o[DOUT]     = f2bf(a1);
  o[2 * DOUT] = f2bf(a2);
  o[3 * DOUT] = f2bf(a3);
}

// ---------------- projection: V, transposed bf16 out Vt[b][64][S] ----------------
__global__ __launch_bounds__(256) void proj_v(
    const float* __restrict__ X, const float* __restrict__ W, ushort* __restrict__ Vt)
{
  __shared__ ushort tile[64][72];
  const int lane  = threadIdx.x & 63;
  const int wv    = threadIdx.x >> 6;
  const int b     = blockIdx.x >> 6;           // 64 blocks per batch
  const int srow0 = (blockIdx.x & 63) * 64;
  const float* xb = X + ((size_t)b * S_LEN + srow0) * DIN;
#pragma unroll
  for (int rr = 0; rr < 16; rr += 4) {
    const int r0 = wv * 16 + rr;
    const float* x = xb + (size_t)r0 * DIN;
    float a0 = 0.f, a1 = 0.f, a2 = 0.f, a3 = 0.f;
#pragma unroll 4
    for (int k = 0; k < DIN; k += 4) {
      float4 x0 = *(const float4*)(x + k);
      float4 x1 = *(const float4*)(x + DIN + k);
      float4 x2 = *(const float4*)(x + 2 * DIN + k);
      float4 x3 = *(const float4*)(x + 3 * DIN + k);
      float w0 = W[(k + 0) * DOUT + lane];
      float w1 = W[(k + 1) * DOUT + lane];
      float w2 = W[(k + 2) * DOUT + lane];
      float w3 = W[(k + 3) * DOUT + lane];
      a0 += x0.x * w0 + x0.y * w1 + x0.z * w2 + x0.w * w3;
      a1 += x1.x * w0 + x1.y * w1 + x1.z * w2 + x1.w * w3;
      a2 += x2.x * w0 + x2.y * w1 + x2.z * w2 + x2.w * w3;
      a3 += x3.x * w0 + x3.y * w1 + x3.z * w2 + x3.w * w3;
    }
    tile[r0 + 0][lane] = f2bf(a0);
    tile[r0 + 1][lane] = f2bf(a1);
    tile[r0 + 2][lane] = f2bf(a2);
    tile[r0 + 3][lane] = f2bf(a3);
  }
  __syncthreads();
  const int f  = threadIdx.x >> 2;             // 0..63 output feature
  const int rb = (threadIdx.x & 3) * 16;       // row chunk
  ushort v[16];
#pragma unroll
  for (int i = 0; i < 16; ++i) v[i] = tile[rb + i][f];
  ushort* dst = Vt + ((size_t)b * DOUT + f) * S_LEN + srow0 + rb;
  *(short8*)dst        = *(short8*)v;
  *(short8*)(dst + 8)  = *((short8*)v + 1);
}

// ---------------- flash attention, causal, 16 Q-rows/block, 4 waves stripe KV ----------------
__global__ __launch_bounds__(256) void attn_kernel(
    const ushort* __restrict__ Qb, const ushort* __restrict__ Kb,
    const ushort* __restrict__ Vt, float* __restrict__ Out)
{
  __shared__ ushort plds[4][16][72];   // per-wave P transpose staging (+8 pad)
  __shared__ float  mbuf[4][16];
  __shared__ float  lbuf[4][16];
  __shared__ float  obuf[4][16][64];

  const int tid  = threadIdx.x;
  const int lane = tid & 63;
  const int w    = tid >> 6;
  const int l15  = lane & 15;
  const int hi   = lane >> 4;          // 0..3
  const int b    = blockIdx.y;
  const int qbase = blockIdx.x * 16;

  // Q A-fragments (held in registers for the whole block)
  const ushort* Qp = Qb + ((size_t)(b * S_LEN + qbase + l15)) * DOUT + hi * 8;
  short8 qA0 = *(const short8*)Qp;
  short8 qA1 = *(const short8*)(Qp + 32);

  float m[4], l[4];
  f32x4 acc[4];
#pragma unroll
  for (int r = 0; r < 4; ++r) { m[r] = -INFINITY; l[r] = 0.f; }
#pragma unroll
  for (int ft = 0; ft < 4; ++ft) acc[ft] = (f32x4){0.f, 0.f, 0.f, 0.f};

  const float cf = 1.44269504088896340736f / 64.0f;   // log2(e)/sqrt(4096)
  const int ntiles = ((qbase + 15) >> 6) + 1;
  const ushort* Kbase = Kb + (size_t)b * S_LEN * DOUT;
  const ushort* Vbase = Vt + (size_t)b * DOUT * S_LEN;

  for (int t = w; t < ntiles; t += 4) {
    const int kv = t * KB;
    // --- QK^T : 4 key-subtiles x (K=64 via 2 slices) ---
    f32x4 sc[4];
#pragma unroll
    for (int sub = 0; sub < 4; ++sub) {
      const ushort* kp = Kbase + (size_t)(kv + sub * 16 + l15) * DOUT + hi * 8;
      short8 kf0 = *(const short8*)kp;
      short8 kf1 = *(const short8*)(kp + 32);
      f32x4 s = (f32x4){0.f, 0.f, 0.f, 0.f};
      s = __builtin_amdgcn_mfma_f32_16x16x32_bf16(qA0, kf0, s, 0, 0, 0);
      s = __builtin_amdgcn_mfma_f32_16x16x32_bf16(qA1, kf1, s, 0, 0, 0);
      sc[sub] = s;
    }
    // --- scale + causal mask (exp2 domain) ---
    float lv[4][4];
#pragma unroll
    for (int sub = 0; sub < 4; ++sub)
#pragma unroll
      for (int r = 0; r < 4; ++r) {
        float v = sc[sub][r] * cf;
        int qg = qbase + hi * 4 + r;
        int kg = kv + sub * 16 + l15;
        lv[sub][r] = (kg > qg) ? -INFINITY : v;
      }
    // --- row max (in-lane over 4 tiles, then across 16 lanes) ---
    float tm[4], rs[4], sf[4], P[4][4];
#pragma unroll
    for (int r = 0; r < 4; ++r)
      tm[r] = fmaxf(fmaxf(lv[0][r], lv[1][r]), fmaxf(lv[2][r], lv[3][r]));
#pragma unroll
    for (int msk = 1; msk < 16; msk <<= 1)
#pragma unroll
      for (int r = 0; r < 4; ++r)
        tm[r] = fmaxf(tm[r], __shfl_xor(tm[r], msk, 64));
    // --- online-softmax update ---
#pragma unroll
    for (int r = 0; r < 4; ++r) {
      float mn = fmaxf(m[r], tm[r]);
      float msafe = (mn == -INFINITY) ? 0.f : mn;   // avoid -inf - -inf = NaN
      sf[r] = exp2f(m[r] - msafe);
      m[r] = mn;
      float s0 = 0.f;
#pragma unroll
      for (int sub = 0; sub < 4; ++sub) {
        float p = exp2f(lv[sub][r] - msafe);
        P[sub][r] = p;
        s0 += p;
      }
      rs[r] = s0;
    }
#pragma unroll
    for (int msk = 1; msk < 16; msk <<= 1)
#pragma unroll
      for (int r = 0; r < 4; ++r)
        rs[r] += __shfl_xor(rs[r], msk, 64);
#pragma unroll
    for (int r = 0; r < 4; ++r) {
      l[r] = l[r] * sf[r] + rs[r];
#pragma unroll
      for (int ft = 0; ft < 4; ++ft) acc[ft][r] *= sf[r];
    }
    // --- P -> bf16 via LDS (per-wave region, no barrier needed) ---
#pragma unroll
    for (int sub = 0; sub < 4; ++sub)
#pragma unroll
      for (int r = 0; r < 4; ++r)
        plds[w][hi * 4 + r][sub * 16 + l15] = f2bf(P[sub][r]);
    // --- PV : O += P * V ---
#pragma unroll
    for (int ks = 0; ks < 2; ++ks) {
      short8 pA = *(const short8*)&plds[w][l15][ks * 32 + hi * 8];
#pragma unroll
      for (int ft = 0; ft < 4; ++ft) {
        const ushort* vp = Vbase + (size_t)(ft * 16 + l15) * S_LEN + kv + ks * 32 + hi * 8;
        short8 vB = *(const short8*)vp;
        acc[ft] = __builtin_amdgcn_mfma_f32_16x16x32_bf16(pA, vB, acc[ft], 0, 0, 0);
      }
    }
  }

  // --- write per-wave partials, merge across the 4 KV-stripe waves ---
  if (l15 == 0) {
#pragma unroll
    for (int r = 0; r < 4; ++r) { mbuf[w][hi * 4 + r] = m[r]; lbuf[w][hi * 4 + r] = l[r]; }
  }
#pragma unroll
  for (int ft = 0; ft < 4; ++ft)
#pragma unroll
    for (int r = 0; r < 4; ++r)
      obuf[w][hi * 4 + r][ft * 16 + l15] = acc[ft][r];
  __syncthreads();

  const int row = tid >> 4;        // 0..15
  const int cs  = (tid & 15) * 4;  // 4 output cols per thread
  float mw[4], ew[4];
  float M = -INFINITY;
#pragma unroll
  for (int i = 0; i < 4; ++i) { mw[i] = mbuf[i][row]; M = fmaxf(M, mw[i]); }
  float L = 0.f;
#pragma unroll
  for (int i = 0; i < 4; ++i) { ew[i] = exp2f(mw[i] - M); L += lbuf[i][row] * ew[i]; }
  const float inv = 1.f / L;
  float4 o;
#pragma unroll
  for (int c = 0; c < 4; ++c) {
    float a = 0.f;
#pragma unroll
    for (int i = 0; i < 4; ++i) a += obuf[i][row][cs + c] * ew[i];
    ((float*)&o)[c] = a * inv;
  }
  *(float4*)(Out + ((size_t)(b * S_LEN + qbase + row)) * DOUT + cs) = o;
}

extern "C" void kernel_launch(void* const* d_in, const int* in_sizes, int n_in,
                              void* d_out, int out_size, void* d_ws, size_t ws_size,
                              hipStream_t stream) {
  const float* Xk = (const float*)d_in[0];
  const float* Xv = (const float*)d_in[1];
  const float* Xq = (const float*)d_in[2];
  const float* Wk = (const float*)d_in[3];
  const float* Wv = (const float*)d_in[4];
  const float* Wq = (const float*)d_in[5];
  float* Out = (float*)d_out;

  ushort* Kb = (ushort*)d_ws;                               // [B][S][64] bf16
  ushort* Qb = Kb + (size_t)NBATCH * S_LEN * DOUT;          // [B][S][64] bf16
  ushort* Vt = Qb + (size_t)NBATCH * S_LEN * DOUT;          // [B][64][S] bf16

  proj_qk<<<dim3(NBATCH * S_LEN / 16, 2), 256, 0, stream>>>(Xk, Wk, Kb, Xq, Wq, Qb);
  proj_v<<<dim3(NBATCH * S_LEN / 64), 256, 0, stream>>>(Xv, Wv, Vt);
  attn_kernel<<<dim3(S_LEN / 16, NBATCH), 256, 0, stream>>>(Qb, Kb, Vt, Out);
}